// Round 17
// baseline (250.974 us; speedup 1.0000x reference)
//
#include <hip/hip_runtime.h>

#define N_NODES 20000
#define N_EDGES 320000
#define C 64
#define NATTR 10
#define MSG_DIM 576      // C*(1+3+5)
#define WC_COLS 192      // 3*C
#define PRE 12           // per-wave snd/xs prefetch depth
#define REC 20           // merged record: ef[0..8) ea[8..17) snd@17 pad[18,19]

// ---------------------------------------------------------------------------
// Kernel 1: h = node_feats @ (W_lin1/8) + receiver histogram + skip-path
// sc[n,w] = sum_{u,v} h[n,u]*attrs[n,v]*W_skip[u,v,w]/sqrt(640), with h kept
// in LDS between phases (no global h re-read, one fewer dispatch).
// ---------------------------------------------------------------------------
__global__ __launch_bounds__(256) void node_linear_hist_skip(
        const float* __restrict__ nf,
        const float* __restrict__ W,
        float* __restrict__ h,
        const int* __restrict__ eidx,
        int* __restrict__ counts,
        const float* __restrict__ attrs,
        const float* __restrict__ Wskip,   // 64*10*64
        float* __restrict__ sc) {
    const int t = threadIdx.x;
    {   // histogram: one edge per thread (1250*256 == N_EDGES)
        const int e = blockIdx.x * 256 + t;
        atomicAdd(&counts[eidx[N_EDGES + e]], 1);
    }
    __shared__ float Ws[64 * 64];
    __shared__ float row[4][64];
    __shared__ float hl[16][64];
    const int lane = t & 63, wv = t >> 6;
    for (int i = t; i < 4096; i += 256) Ws[i] = W[i] * 0.125f;
    __syncthreads();
    const int base = blockIdx.x * 16;
    #pragma unroll 1
    for (int it = 0; it < 4; ++it) {
        const int nl = it * 4 + wv;
        const int n = base + nl;
        row[wv][lane] = nf[(size_t)n * 64 + lane];
        float acc = 0.f;
        #pragma unroll
        for (int k = 0; k < 64; ++k) acc += row[wv][k] * Ws[k * 64 + lane];
        h[(size_t)n * 64 + lane] = acc;
        hl[nl][lane] = acc;
    }
    __syncthreads();

    // ---- skip phase: thread (wv,lane) handles local nodes {wv+4i} ----
    float alr[4][NATTR];
    #pragma unroll
    for (int i = 0; i < 4; ++i) {
        const float* ap = attrs + (size_t)(base + wv + 4 * i) * NATTR;
        #pragma unroll
        for (int v = 0; v < NATTR; ++v) alr[i][v] = ap[v];
    }
    float acc[4] = {0.f, 0.f, 0.f, 0.f};
    #pragma unroll 1
    for (int u4 = 0; u4 < 16; ++u4) {
        const int u0 = u4 * 4;
        float4 hu[4];
        #pragma unroll
        for (int i = 0; i < 4; ++i)
            hu[i] = *reinterpret_cast<const float4*>(&hl[wv + 4 * i][u0]);
        #pragma unroll
        for (int uu = 0; uu < 4; ++uu) {
            float tmp[4] = {0.f, 0.f, 0.f, 0.f};
            #pragma unroll
            for (int v = 0; v < NATTR; ++v) {
                const float wk = Wskip[((u0 + uu) * NATTR + v) * 64 + lane];
                #pragma unroll
                for (int i = 0; i < 4; ++i) tmp[i] += alr[i][v] * wk;
            }
            #pragma unroll
            for (int i = 0; i < 4; ++i) {
                const float huv = (uu == 0) ? hu[i].x : (uu == 1) ? hu[i].y
                                 : (uu == 2) ? hu[i].z : hu[i].w;
                acc[i] += huv * tmp[i];
            }
        }
    }
    const float scale = 0.03952847075210474f;  // 1/sqrt(640)
    #pragma unroll
    for (int i = 0; i < 4; ++i)
        sc[(size_t)(base + wv + 4 * i) * 64 + lane] = acc[i] * scale;
}

// ---------------------------------------------------------------------------
// Kernel 2 (FUSED 1-block): prefix scan + radial collapse + rec pad zeroing.
// ---------------------------------------------------------------------------
#define SCAN_PER 20   // 1024 * 20 = 20480 >= 20000
__global__ __launch_bounds__(1024) void scan_radial_kernel(
        const int* __restrict__ counts,
        int* __restrict__ start, int* __restrict__ cursor,
        const float* __restrict__ Wr0, const float* __restrict__ Wr1,
        const float* __restrict__ Wr2, const float* __restrict__ Wr3,
        float* __restrict__ Wc, float* __restrict__ rec) {
    __shared__ int wsum[16];
    __shared__ float T[8 * 64];
    __shared__ float T2[8 * 64];
    const int t = threadIdx.x, lane = t & 63, w = t >> 6;
    const float s0r = 0.35355339059327373f;  // 1/sqrt(8)
    const float s1r = 0.125f;                // 1/8

    const int base = t * SCAN_PER;
    int v[SCAN_PER];
    int s = 0;
    #pragma unroll
    for (int j = 0; j < SCAN_PER; ++j) {
        const int idx = base + j;
        v[j] = (idx < N_NODES) ? counts[idx] : 0;
        s += v[j];
    }
    int sc = s;
    #pragma unroll
    for (int off = 1; off < 64; off <<= 1) {
        int up = __shfl_up(sc, off);
        if (lane >= off) sc += up;
    }
    if (lane == 63) wsum[w] = sc;
    // zero the 16 pad records' snd slots (PRE over-read lands here)
    if (t < 16) rec[(size_t)(N_EDGES + t) * REC + 17] = 0.f;
    for (int i = t; i < 8 * 64; i += 1024) {
        int r = i >> 6, c2 = i & 63;
        float acc = 0.f;
        for (int k = 0; k < 64; ++k) acc += Wr0[r * 64 + k] * Wr1[k * 64 + c2];
        T[i] = acc * (s0r * s1r);
    }
    __syncthreads();
    if (t == 0) {
        int a = 0;
        #pragma unroll
        for (int i = 0; i < 16; ++i) { int x = wsum[i]; wsum[i] = a; a += x; }
    }
    for (int i = t; i < 8 * 64; i += 1024) {
        int r = i >> 6, c2 = i & 63;
        float acc = 0.f;
        for (int k = 0; k < 64; ++k) acc += T[r * 64 + k] * Wr2[k * 64 + c2];
        T2[i] = acc * s1r;
    }
    __syncthreads();
    int a = wsum[w] + (sc - s);   // exclusive prefix for this thread
    #pragma unroll
    for (int j = 0; j < SCAN_PER; ++j) {
        const int idx = base + j;
        if (idx < N_NODES) {
            start[idx] = a;
            cursor[idx] = a;
            a += v[j];
        }
    }
    for (int i = t; i < 8 * WC_COLS; i += 1024) {
        int r = i / WC_COLS, c2 = i % WC_COLS;
        float acc = 0.f;
        for (int k = 0; k < 64; ++k) acc += T2[r * 64 + k] * Wr3[k * WC_COLS + c2];
        Wc[i] = acc * s1r;
    }
}

// ---------------------------------------------------------------------------
// Kernel 3: counting-sort scatter -> ONE 80B merged record per edge.
// ---------------------------------------------------------------------------
__global__ void scatter_build(const int* __restrict__ eidx,
                              const float* __restrict__ ef,
                              const float* __restrict__ ea,
                              int* __restrict__ cursor,
                              float* __restrict__ rec) {
    const int e = blockIdx.x * 256 + threadIdx.x;
    if (e >= N_EDGES) return;
    const int r = eidx[N_EDGES + e];
    const int s = eidx[e];
    const int pos = atomicAdd(&cursor[r], 1);
    const float4* f4 = reinterpret_cast<const float4*>(ef + (size_t)e * 8);
    const float* y = ea + (size_t)e * 9;
    float4* o = reinterpret_cast<float4*>(rec + (size_t)pos * REC);
    o[0] = f4[0];
    o[1] = f4[1];
    o[2] = make_float4(y[0], y[1], y[2], y[3]);
    o[3] = make_float4(y[4], y[5], y[6], y[7]);
    o[4] = make_float4(y[8], __int_as_float(s), 0.f, 0.f);
}

// ---------------------------------------------------------------------------
// Kernel 4: gather (2 waves/node, hoisted snd->xs chain, Wc in regs, LDS
// half-combine) reading merged 80B records.
// ---------------------------------------------------------------------------
__global__ __launch_bounds__(256) void gather_sorted(
                              const float* __restrict__ rec,   // (E+16) x REC
                              const float* __restrict__ h,     // N x 64
                              const float* __restrict__ Wc,    // 8 x 192
                              const int* __restrict__ start,
                              const int* __restrict__ counts,
                              float* __restrict__ msg) {       // N x 576
    __shared__ float part[2][9][64];
    const int t = threadIdx.x, lane = t & 63, wv = t >> 6;
    const int g = wv >> 1;               // node slot within block (0,1)
    const int half = wv & 1;             // which half of the edge list
    const int n = blockIdx.x * 2 + g;

    float wc0[8], wc1[8], wc2[8];
    #pragma unroll
    for (int k = 0; k < 8; ++k) {
        wc0[k] = Wc[k * WC_COLS + lane];
        wc1[k] = Wc[k * WC_COLS + 64 + lane];
        wc2[k] = Wc[k * WC_COLS + 128 + lane];
    }

    float p0 = 0.f;
    float p1[3] = {0.f, 0.f, 0.f};
    float p2[5] = {0.f, 0.f, 0.f, 0.f, 0.f};

    if (n < N_NODES) {
        const int s0 = start[n], cnt = counts[n];
        const int jbeg = half ? (cnt >> 1) : 0;
        const int jend = half ? cnt : (cnt >> 1);
        const int m = jend - jbeg;
        const int base = s0 + jbeg;

        if (m > 0) {
            const int P = (m < PRE) ? m : PRE;
            int snd[PRE];
            #pragma unroll
            for (int b = 0; b < PRE; ++b)
                snd[b] = __float_as_int(rec[(size_t)(base + b) * REC + 17]);  // pad-safe
            float xs[PRE];
            #pragma unroll
            for (int b = 0; b < PRE; ++b) {
                const int sb = (b < P) ? snd[b] : snd[0];
                xs[b] = h[(size_t)sb * 64 + lane];
            }
            #pragma unroll
            for (int jj = 0; jj < PRE / 2; ++jj) {
                const int j = jj * 2;
                if (j < P) {
                    const bool has2 = (j + 1 < P);
                    const int j1 = has2 ? (j + 1) : j;
                    const float gate1 = has2 ? 1.f : 0.f;
                    const float4* q0 = reinterpret_cast<const float4*>(rec + (size_t)(base + j) * REC);
                    const float4* q1 = reinterpret_cast<const float4*>(rec + (size_t)(base + j1) * REC);
                    const float4 e00 = q0[0], e01 = q0[1];
                    const float4 a00 = q0[2], a01 = q0[3], a02 = q0[4];
                    const float4 e10 = q1[0], e11 = q1[1];
                    const float4 a10 = q1[2], a11 = q1[3], a12 = q1[4];
                    const float xa = xs[j];
                    const float xb = (has2 ? xs[j + 1] : 0.f) * gate1;
                    {
                        const float* fk = reinterpret_cast<const float*>(&e00);
                        const float* gk = reinterpret_cast<const float*>(&e01);
                        float w0 = fk[0] * wc0[0], w1 = fk[0] * wc1[0], w2 = fk[0] * wc2[0];
                        #pragma unroll
                        for (int k = 1; k < 4; ++k) {
                            w0 += fk[k] * wc0[k]; w1 += fk[k] * wc1[k]; w2 += fk[k] * wc2[k];
                        }
                        #pragma unroll
                        for (int k = 0; k < 4; ++k) {
                            w0 += gk[k] * wc0[k + 4]; w1 += gk[k] * wc1[k + 4]; w2 += gk[k] * wc2[k + 4];
                        }
                        const float b0 = xa * w0, b1 = xa * w1, b2 = xa * w2;
                        p0    += b0 * a00.x;
                        p1[0] += b1 * a00.y; p1[1] += b1 * a00.z; p1[2] += b1 * a00.w;
                        p2[0] += b2 * a01.x; p2[1] += b2 * a01.y; p2[2] += b2 * a01.z;
                        p2[3] += b2 * a01.w; p2[4] += b2 * a02.x;
                    }
                    {
                        const float* fk = reinterpret_cast<const float*>(&e10);
                        const float* gk = reinterpret_cast<const float*>(&e11);
                        float w0 = fk[0] * wc0[0], w1 = fk[0] * wc1[0], w2 = fk[0] * wc2[0];
                        #pragma unroll
                        for (int k = 1; k < 4; ++k) {
                            w0 += fk[k] * wc0[k]; w1 += fk[k] * wc1[k]; w2 += fk[k] * wc2[k];
                        }
                        #pragma unroll
                        for (int k = 0; k < 4; ++k) {
                            w0 += gk[k] * wc0[k + 4]; w1 += gk[k] * wc1[k + 4]; w2 += gk[k] * wc2[k + 4];
                        }
                        const float b0 = xb * w0, b1 = xb * w1, b2 = xb * w2;
                        p0    += b0 * a10.x;
                        p1[0] += b1 * a10.y; p1[1] += b1 * a10.z; p1[2] += b1 * a10.w;
                        p2[0] += b2 * a11.x; p2[1] += b2 * a11.y; p2[2] += b2 * a11.z;
                        p2[3] += b2 * a11.w; p2[4] += b2 * a12.x;
                    }
                }
            }
            for (int j = PRE; j < m; ++j) {   // rare tail m > PRE
                const float4* q = reinterpret_cast<const float4*>(rec + (size_t)(base + j) * REC);
                const float4 fa = q[0], fb = q[1];
                const float4 ya = q[2], yb = q[3], yc = q[4];
                const int snd_t = __float_as_int(yc.y);
                const float xs_t = h[(size_t)snd_t * 64 + lane];
                const float* fk = reinterpret_cast<const float*>(&fa);
                const float* gk = reinterpret_cast<const float*>(&fb);
                float w0 = fk[0] * wc0[0], w1 = fk[0] * wc1[0], w2 = fk[0] * wc2[0];
                #pragma unroll
                for (int k = 1; k < 4; ++k) {
                    w0 += fk[k] * wc0[k]; w1 += fk[k] * wc1[k]; w2 += fk[k] * wc2[k];
                }
                #pragma unroll
                for (int k = 0; k < 4; ++k) {
                    w0 += gk[k] * wc0[k + 4]; w1 += gk[k] * wc1[k + 4]; w2 += gk[k] * wc2[k + 4];
                }
                const float b0 = xs_t * w0, b1 = xs_t * w1, b2 = xs_t * w2;
                p0    += b0 * ya.x;
                p1[0] += b1 * ya.y; p1[1] += b1 * ya.z; p1[2] += b1 * ya.w;
                p2[0] += b2 * yb.x; p2[1] += b2 * yb.y; p2[2] += b2 * yb.z;
                p2[3] += b2 * yb.w; p2[4] += b2 * yc.x;
            }
        }
    }

    if (half) {
        part[g][0][lane] = p0;
        #pragma unroll
        for (int m2 = 0; m2 < 3; ++m2) part[g][1 + m2][lane] = p1[m2];
        #pragma unroll
        for (int m2 = 0; m2 < 5; ++m2) part[g][4 + m2][lane] = p2[m2];
    }
    __syncthreads();
    if (!half && n < N_NODES) {
        float* mrow = msg + (size_t)n * MSG_DIM;
        mrow[lane] = p0 + part[g][0][lane];
        #pragma unroll
        for (int m2 = 0; m2 < 3; ++m2)
            mrow[64 + lane * 3 + m2] = p1[m2] + part[g][1 + m2][lane];
        #pragma unroll
        for (int m2 = 0; m2 < 5; ++m2)
            mrow[256 + lane * 5 + m2] = p2[m2] + part[g][4 + m2][lane];
    }
}

// ---------------------------------------------------------------------------
// Kernel 5: LEAN out_transform, in place. 16 nodes / block (36 KB stage),
// wave handles 4 rows -> W loads amortized 4x; W from global (coalesced).
// ---------------------------------------------------------------------------
__global__ __launch_bounds__(256) void out_transform(
        const float* __restrict__ Wmsg,  // 3*64*64
        float* __restrict__ out) {       // N x 576 (in = msg, out in place)
    __shared__ __align__(16) float stage[16 * MSG_DIM];  // 36 KB
    const int t = threadIdx.x, lane = t & 63, wv = t >> 6;
    {
        const float4* src = reinterpret_cast<const float4*>(
            out + (size_t)blockIdx.x * 16 * MSG_DIM);
        float4* dst = reinterpret_cast<float4*>(stage);
        #pragma unroll
        for (int i = 0; i < 9; ++i) dst[t + 256 * i] = src[t + 256 * i];
    }
    __syncthreads();
    const float scale = 1.f / 128.f;  // 1/(sqrt(64)*16)

    const int r0 = wv * 4;
    float o[4][9] = {};
    #pragma unroll 1
    for (int c = 0; c < 16; ++c) {
        const int u0 = c * 4;
        float w0[4], w1[4], w2[4];
        #pragma unroll
        for (int k = 0; k < 4; ++k) {
            w0[k] = Wmsg[(u0 + k) * 64 + lane];
            w1[k] = Wmsg[4096 + (u0 + k) * 64 + lane];
            w2[k] = Wmsg[8192 + (u0 + k) * 64 + lane];
        }
        #pragma unroll
        for (int rr = 0; rr < 4; ++rr) {
            const float* row = stage + (size_t)(r0 + rr) * MSG_DIM;
            float* o9 = o[rr];
            const float4 c0 = *reinterpret_cast<const float4*>(row + u0);
            const float4 c1a = *reinterpret_cast<const float4*>(row + 64 + u0 * 3);
            const float4 c1b = *reinterpret_cast<const float4*>(row + 64 + u0 * 3 + 4);
            const float4 c1c = *reinterpret_cast<const float4*>(row + 64 + u0 * 3 + 8);
            const float4 c2a = *reinterpret_cast<const float4*>(row + 256 + u0 * 5);
            const float4 c2b = *reinterpret_cast<const float4*>(row + 256 + u0 * 5 + 4);
            const float4 c2c = *reinterpret_cast<const float4*>(row + 256 + u0 * 5 + 8);
            const float4 c2d = *reinterpret_cast<const float4*>(row + 256 + u0 * 5 + 12);
            const float4 c2e = *reinterpret_cast<const float4*>(row + 256 + u0 * 5 + 16);
            o9[0] += c0.x * w0[0] + c0.y * w0[1] + c0.z * w0[2] + c0.w * w0[3];
            o9[1] += c1a.x * w1[0] + c1a.w * w1[1] + c1b.z * w1[2] + c1c.y * w1[3];
            o9[2] += c1a.y * w1[0] + c1b.x * w1[1] + c1b.w * w1[2] + c1c.z * w1[3];
            o9[3] += c1a.z * w1[0] + c1b.y * w1[1] + c1c.x * w1[2] + c1c.w * w1[3];
            o9[4] += c2a.x * w2[0] + c2b.y * w2[1] + c2c.z * w2[2] + c2d.w * w2[3];
            o9[5] += c2a.y * w2[0] + c2b.z * w2[1] + c2c.w * w2[2] + c2e.x * w2[3];
            o9[6] += c2a.z * w2[0] + c2b.w * w2[1] + c2d.x * w2[2] + c2e.y * w2[3];
            o9[7] += c2a.w * w2[0] + c2c.x * w2[1] + c2d.y * w2[2] + c2e.z * w2[3];
            o9[8] += c2b.x * w2[0] + c2c.y * w2[1] + c2d.z * w2[2] + c2e.w * w2[3];
        }
    }
    #pragma unroll
    for (int rr = 0; rr < 4; ++rr) {
        float* op = out + ((size_t)blockIdx.x * 16 + r0 + rr) * MSG_DIM + lane * 9;
        #pragma unroll
        for (int m = 0; m < 9; ++m) op[m] = o[rr][m] * scale;
    }
}

// ---------------------------------------------------------------------------
extern "C" void kernel_launch(void* const* d_in, const int* in_sizes, int n_in,
                              void* d_out, int out_size, void* d_ws, size_t ws_size,
                              hipStream_t stream) {
    const float* node_attrs = (const float*)d_in[0];
    const float* node_feats = (const float*)d_in[1];
    const float* edge_attrs = (const float*)d_in[2];
    const float* edge_feats = (const float*)d_in[3];
    const int*   edge_index = (const int*)d_in[4];
    const float* W_lin1 = (const float*)d_in[5];
    const float* W_r0 = (const float*)d_in[6];
    const float* W_r1 = (const float*)d_in[7];
    const float* W_r2 = (const float*)d_in[8];
    const float* W_r3 = (const float*)d_in[9];
    const float* W_msg = (const float*)d_in[10];
    const float* W_skip = (const float*)d_in[11];

    float* out = (float*)d_out;                       // N x 576 (msg -> transformed in place)
    float* sc  = out + (size_t)N_NODES * MSG_DIM;     // N x 64

    float* wsf = (float*)d_ws;
    float* Wc = wsf;                          // 2048 floats
    float* h  = wsf + 2048;                   // N*64
    int* wsi   = (int*)(wsf + 2048 + (size_t)N_NODES * 64);
    int* counts = wsi;                        // N
    int* start  = wsi + N_NODES;              // N
    int* cursor = wsi + 2 * N_NODES;          // N
    float* rec  = (float*)(wsi + 3 * N_NODES);        // (E+16) * REC floats

    hipMemsetAsync(counts, 0, N_NODES * sizeof(int), stream);
    node_linear_hist_skip<<<1250, 256, 0, stream>>>(node_feats, W_lin1, h,
                                                    edge_index, counts,
                                                    node_attrs, W_skip, sc);
    scan_radial_kernel<<<1, 1024, 0, stream>>>(counts, start, cursor,
                                               W_r0, W_r1, W_r2, W_r3, Wc, rec);
    scatter_build<<<1250, 256, 0, stream>>>(
        edge_index, edge_feats, edge_attrs, cursor, rec);
    gather_sorted<<<(N_NODES + 1) / 2, 256, 0, stream>>>(
        rec, h, Wc, start, counts, out);
    out_transform<<<1250, 256, 0, stream>>>(W_msg, out);
}

// Round 18
// 221.569 us; speedup vs baseline: 1.1327x; 1.1327x over previous
//
#include <hip/hip_runtime.h>

#define N_NODES 20000
#define N_EDGES 320000
#define C 64
#define NATTR 10
#define MSG_DIM 576      // C*(1+3+5)
#define WC_COLS 192      // 3*C
#define PRE 12           // per-wave edge capacity via LDS staging
#define REC 20           // merged record: ef[0..8) ea[8..17) snd@17 pad[18,19]

// ---------------------------------------------------------------------------
// Kernel 1: h = node_feats @ (W_lin1/8) + receiver histogram + skip-path
// (h kept in LDS between phases; one fewer dispatch).
// ---------------------------------------------------------------------------
__global__ __launch_bounds__(256) void node_linear_hist_skip(
        const float* __restrict__ nf,
        const float* __restrict__ W,
        float* __restrict__ h,
        const int* __restrict__ eidx,
        int* __restrict__ counts,
        const float* __restrict__ attrs,
        const float* __restrict__ Wskip,   // 64*10*64
        float* __restrict__ sc) {
    const int t = threadIdx.x;
    {   // histogram: one edge per thread (1250*256 == N_EDGES)
        const int e = blockIdx.x * 256 + t;
        atomicAdd(&counts[eidx[N_EDGES + e]], 1);
    }
    __shared__ float Ws[64 * 64];
    __shared__ float row[4][64];
    __shared__ float hl[16][64];
    const int lane = t & 63, wv = t >> 6;
    for (int i = t; i < 4096; i += 256) Ws[i] = W[i] * 0.125f;
    __syncthreads();
    const int base = blockIdx.x * 16;
    #pragma unroll 1
    for (int it = 0; it < 4; ++it) {
        const int nl = it * 4 + wv;
        const int n = base + nl;
        row[wv][lane] = nf[(size_t)n * 64 + lane];
        float acc = 0.f;
        #pragma unroll
        for (int k = 0; k < 64; ++k) acc += row[wv][k] * Ws[k * 64 + lane];
        h[(size_t)n * 64 + lane] = acc;
        hl[nl][lane] = acc;
    }
    __syncthreads();

    float alr[4][NATTR];
    #pragma unroll
    for (int i = 0; i < 4; ++i) {
        const float* ap = attrs + (size_t)(base + wv + 4 * i) * NATTR;
        #pragma unroll
        for (int v = 0; v < NATTR; ++v) alr[i][v] = ap[v];
    }
    float acc[4] = {0.f, 0.f, 0.f, 0.f};
    #pragma unroll 1
    for (int u4 = 0; u4 < 16; ++u4) {
        const int u0 = u4 * 4;
        float4 hu[4];
        #pragma unroll
        for (int i = 0; i < 4; ++i)
            hu[i] = *reinterpret_cast<const float4*>(&hl[wv + 4 * i][u0]);
        #pragma unroll
        for (int uu = 0; uu < 4; ++uu) {
            float tmp[4] = {0.f, 0.f, 0.f, 0.f};
            #pragma unroll
            for (int v = 0; v < NATTR; ++v) {
                const float wk = Wskip[((u0 + uu) * NATTR + v) * 64 + lane];
                #pragma unroll
                for (int i = 0; i < 4; ++i) tmp[i] += alr[i][v] * wk;
            }
            #pragma unroll
            for (int i = 0; i < 4; ++i) {
                const float huv = (uu == 0) ? hu[i].x : (uu == 1) ? hu[i].y
                                 : (uu == 2) ? hu[i].z : hu[i].w;
                acc[i] += huv * tmp[i];
            }
        }
    }
    const float scale = 0.03952847075210474f;  // 1/sqrt(640)
    #pragma unroll
    for (int i = 0; i < 4; ++i)
        sc[(size_t)(base + wv + 4 * i) * 64 + lane] = acc[i] * scale;
}

// ---------------------------------------------------------------------------
// Kernel 2 (FUSED 1-block): prefix scan + radial collapse + rec pad zeroing.
// ---------------------------------------------------------------------------
#define SCAN_PER 20   // 1024 * 20 = 20480 >= 20000
__global__ __launch_bounds__(1024) void scan_radial_kernel(
        const int* __restrict__ counts,
        int* __restrict__ start, int* __restrict__ cursor,
        const float* __restrict__ Wr0, const float* __restrict__ Wr1,
        const float* __restrict__ Wr2, const float* __restrict__ Wr3,
        float* __restrict__ Wc, float* __restrict__ rec) {
    __shared__ int wsum[16];
    __shared__ float T[8 * 64];
    __shared__ float T2[8 * 64];
    const int t = threadIdx.x, lane = t & 63, w = t >> 6;
    const float s0r = 0.35355339059327373f;  // 1/sqrt(8)
    const float s1r = 0.125f;                // 1/8

    const int base = t * SCAN_PER;
    int v[SCAN_PER];
    int s = 0;
    #pragma unroll
    for (int j = 0; j < SCAN_PER; ++j) {
        const int idx = base + j;
        v[j] = (idx < N_NODES) ? counts[idx] : 0;
        s += v[j];
    }
    int sc = s;
    #pragma unroll
    for (int off = 1; off < 64; off <<= 1) {
        int up = __shfl_up(sc, off);
        if (lane >= off) sc += up;
    }
    if (lane == 63) wsum[w] = sc;
    // zero the 16 pad records' snd slots (staging over-read lands here)
    if (t < 16) rec[(size_t)(N_EDGES + t) * REC + 17] = 0.f;
    for (int i = t; i < 8 * 64; i += 1024) {
        int r = i >> 6, c2 = i & 63;
        float acc = 0.f;
        for (int k = 0; k < 64; ++k) acc += Wr0[r * 64 + k] * Wr1[k * 64 + c2];
        T[i] = acc * (s0r * s1r);
    }
    __syncthreads();
    if (t == 0) {
        int a = 0;
        #pragma unroll
        for (int i = 0; i < 16; ++i) { int x = wsum[i]; wsum[i] = a; a += x; }
    }
    for (int i = t; i < 8 * 64; i += 1024) {
        int r = i >> 6, c2 = i & 63;
        float acc = 0.f;
        for (int k = 0; k < 64; ++k) acc += T[r * 64 + k] * Wr2[k * 64 + c2];
        T2[i] = acc * s1r;
    }
    __syncthreads();
    int a = wsum[w] + (sc - s);   // exclusive prefix for this thread
    #pragma unroll
    for (int j = 0; j < SCAN_PER; ++j) {
        const int idx = base + j;
        if (idx < N_NODES) {
            start[idx] = a;
            cursor[idx] = a;
            a += v[j];
        }
    }
    for (int i = t; i < 8 * WC_COLS; i += 1024) {
        int r = i / WC_COLS, c2 = i % WC_COLS;
        float acc = 0.f;
        for (int k = 0; k < 64; ++k) acc += T2[r * 64 + k] * Wr3[k * WC_COLS + c2];
        Wc[i] = acc * s1r;
    }
}

// ---------------------------------------------------------------------------
// Kernel 3: counting-sort scatter -> ONE 80B merged record per edge.
// ---------------------------------------------------------------------------
__global__ void scatter_build(const int* __restrict__ eidx,
                              const float* __restrict__ ef,
                              const float* __restrict__ ea,
                              int* __restrict__ cursor,
                              float* __restrict__ rec) {
    const int e = blockIdx.x * 256 + threadIdx.x;
    if (e >= N_EDGES) return;
    const int r = eidx[N_EDGES + e];
    const int s = eidx[e];
    const int pos = atomicAdd(&cursor[r], 1);
    const float4* f4 = reinterpret_cast<const float4*>(ef + (size_t)e * 8);
    const float* y = ea + (size_t)e * 9;
    float4* o = reinterpret_cast<float4*>(rec + (size_t)pos * REC);
    o[0] = f4[0];
    o[1] = f4[1];
    o[2] = make_float4(y[0], y[1], y[2], y[3]);
    o[3] = make_float4(y[4], y[5], y[6], y[7]);
    o[4] = make_float4(y[8], __int_as_float(s), 0.f, 0.f);
}

// ---------------------------------------------------------------------------
// Kernel 4: gather v2 — COOPERATIVE LDS STAGING. A wave's <=12 records are
// contiguous (240 floats): lanes 0..59 fetch them all in ONE coalesced
// float4 load into per-wave LDS; compute reads uniform-address ds_read_b128
// broadcasts with immediate offsets. VMEM ops/wave: ~84 -> ~14.
// ---------------------------------------------------------------------------
__global__ __launch_bounds__(256) void gather_sorted(
                              const float* __restrict__ rec,   // (E+16) x REC
                              const float* __restrict__ h,     // N x 64
                              const float* __restrict__ Wc,    // 8 x 192
                              const int* __restrict__ start,
                              const int* __restrict__ counts,
                              float* __restrict__ msg) {       // N x 576
    __shared__ float part[2][9][64];
    __shared__ __align__(16) float erec[4][PRE * REC];   // 4 x 240 floats
    const int t = threadIdx.x, lane = t & 63, wv = t >> 6;
    const int g = wv >> 1;               // node slot within block (0,1)
    const int half = wv & 1;             // which half of the edge list
    const int n = blockIdx.x * 2 + g;    // grid is exactly N/2 -> always valid

    float wc0[8], wc1[8], wc2[8];
    #pragma unroll
    for (int k = 0; k < 8; ++k) {
        wc0[k] = Wc[k * WC_COLS + lane];
        wc1[k] = Wc[k * WC_COLS + 64 + lane];
        wc2[k] = Wc[k * WC_COLS + 128 + lane];
    }

    const int s0 = start[n], cnt = counts[n];
    const int jbeg = half ? (cnt >> 1) : 0;
    const int jend = half ? cnt : (cnt >> 1);
    const int m = jend - jbeg;
    const int base = s0 + jbeg;

    // cooperative stage: 12 records = 240 floats in one coalesced load
    if (lane < PRE * REC / 4) {  // 60 lanes
        const float4 v = *reinterpret_cast<const float4*>(
            rec + (size_t)base * REC + lane * 4);
        *reinterpret_cast<float4*>(&erec[wv][lane * 4]) = v;
    }
    __syncthreads();

    float p0 = 0.f;
    float p1[3] = {0.f, 0.f, 0.f};
    float p2[5] = {0.f, 0.f, 0.f, 0.f, 0.f};

    const int P = (m < PRE) ? m : PRE;
    // hoist snd (from LDS) then all h gathers
    int snd[PRE];
    #pragma unroll
    for (int b = 0; b < PRE; ++b) snd[b] = __float_as_int(erec[wv][b * REC + 17]);
    float xs[PRE];
    #pragma unroll
    for (int b = 0; b < PRE; ++b) {
        const int sb = (b < P) ? snd[b] : snd[0];   // always a valid index
        xs[b] = h[(size_t)sb * 64 + lane];
    }

    #pragma unroll
    for (int j = 0; j < PRE; ++j) {
        if (j < P) {   // wave-uniform predicate
            const float* er = &erec[wv][j * REC];
            const float4 e0 = *reinterpret_cast<const float4*>(er);
            const float4 e1 = *reinterpret_cast<const float4*>(er + 4);
            const float4 ya = *reinterpret_cast<const float4*>(er + 8);
            const float4 yb = *reinterpret_cast<const float4*>(er + 12);
            const float  y8 = er[16];
            const float* fk = reinterpret_cast<const float*>(&e0);
            const float* gk = reinterpret_cast<const float*>(&e1);
            float w0 = fk[0] * wc0[0], w1 = fk[0] * wc1[0], w2 = fk[0] * wc2[0];
            #pragma unroll
            for (int k = 1; k < 4; ++k) {
                w0 += fk[k] * wc0[k]; w1 += fk[k] * wc1[k]; w2 += fk[k] * wc2[k];
            }
            #pragma unroll
            for (int k = 0; k < 4; ++k) {
                w0 += gk[k] * wc0[k + 4]; w1 += gk[k] * wc1[k + 4]; w2 += gk[k] * wc2[k + 4];
            }
            const float b0 = xs[j] * w0, b1 = xs[j] * w1, b2 = xs[j] * w2;
            p0    += b0 * ya.x;
            p1[0] += b1 * ya.y; p1[1] += b1 * ya.z; p1[2] += b1 * ya.w;
            p2[0] += b2 * yb.x; p2[1] += b2 * yb.y; p2[2] += b2 * yb.z;
            p2[3] += b2 * yb.w; p2[4] += b2 * y8;
        }
    }
    // rare tail m > PRE: direct global reads
    for (int j = PRE; j < m; ++j) {
        const float4* q = reinterpret_cast<const float4*>(rec + (size_t)(base + j) * REC);
        const float4 fa = q[0], fb = q[1];
        const float4 ya = q[2], yb = q[3], yc = q[4];
        const int snd_t = __float_as_int(yc.y);
        const float xs_t = h[(size_t)snd_t * 64 + lane];
        const float* fk = reinterpret_cast<const float*>(&fa);
        const float* gk = reinterpret_cast<const float*>(&fb);
        float w0 = fk[0] * wc0[0], w1 = fk[0] * wc1[0], w2 = fk[0] * wc2[0];
        #pragma unroll
        for (int k = 1; k < 4; ++k) {
            w0 += fk[k] * wc0[k]; w1 += fk[k] * wc1[k]; w2 += fk[k] * wc2[k];
        }
        #pragma unroll
        for (int k = 0; k < 4; ++k) {
            w0 += gk[k] * wc0[k + 4]; w1 += gk[k] * wc1[k + 4]; w2 += gk[k] * wc2[k + 4];
        }
        const float b0 = xs_t * w0, b1 = xs_t * w1, b2 = xs_t * w2;
        p0    += b0 * ya.x;
        p1[0] += b1 * ya.y; p1[1] += b1 * ya.z; p1[2] += b1 * ya.w;
        p2[0] += b2 * yb.x; p2[1] += b2 * yb.y; p2[2] += b2 * yb.z;
        p2[3] += b2 * yb.w; p2[4] += b2 * yc.x;
    }

    if (half) {
        part[g][0][lane] = p0;
        #pragma unroll
        for (int m2 = 0; m2 < 3; ++m2) part[g][1 + m2][lane] = p1[m2];
        #pragma unroll
        for (int m2 = 0; m2 < 5; ++m2) part[g][4 + m2][lane] = p2[m2];
    }
    __syncthreads();
    if (!half) {
        float* mrow = msg + (size_t)n * MSG_DIM;
        mrow[lane] = p0 + part[g][0][lane];
        #pragma unroll
        for (int m2 = 0; m2 < 3; ++m2)
            mrow[64 + lane * 3 + m2] = p1[m2] + part[g][1 + m2][lane];
        #pragma unroll
        for (int m2 = 0; m2 < 5; ++m2)
            mrow[256 + lane * 5 + m2] = p2[m2] + part[g][4 + m2][lane];
    }
}

// ---------------------------------------------------------------------------
// Kernel 5: LEAN out_transform, in place. 16 nodes / block (36 KB stage),
// wave handles 4 rows; W from global (coalesced, L2-hot).
// ---------------------------------------------------------------------------
__global__ __launch_bounds__(256) void out_transform(
        const float* __restrict__ Wmsg,  // 3*64*64
        float* __restrict__ out) {       // N x 576 (in = msg, out in place)
    __shared__ __align__(16) float stage[16 * MSG_DIM];  // 36 KB
    const int t = threadIdx.x, lane = t & 63, wv = t >> 6;
    {
        const float4* src = reinterpret_cast<const float4*>(
            out + (size_t)blockIdx.x * 16 * MSG_DIM);
        float4* dst = reinterpret_cast<float4*>(stage);
        #pragma unroll
        for (int i = 0; i < 9; ++i) dst[t + 256 * i] = src[t + 256 * i];
    }
    __syncthreads();
    const float scale = 1.f / 128.f;  // 1/(sqrt(64)*16)

    const int r0 = wv * 4;
    float o[4][9] = {};
    #pragma unroll 1
    for (int c = 0; c < 16; ++c) {
        const int u0 = c * 4;
        float w0[4], w1[4], w2[4];
        #pragma unroll
        for (int k = 0; k < 4; ++k) {
            w0[k] = Wmsg[(u0 + k) * 64 + lane];
            w1[k] = Wmsg[4096 + (u0 + k) * 64 + lane];
            w2[k] = Wmsg[8192 + (u0 + k) * 64 + lane];
        }
        #pragma unroll
        for (int rr = 0; rr < 4; ++rr) {
            const float* row = stage + (size_t)(r0 + rr) * MSG_DIM;
            float* o9 = o[rr];
            const float4 c0 = *reinterpret_cast<const float4*>(row + u0);
            const float4 c1a = *reinterpret_cast<const float4*>(row + 64 + u0 * 3);
            const float4 c1b = *reinterpret_cast<const float4*>(row + 64 + u0 * 3 + 4);
            const float4 c1c = *reinterpret_cast<const float4*>(row + 64 + u0 * 3 + 8);
            const float4 c2a = *reinterpret_cast<const float4*>(row + 256 + u0 * 5);
            const float4 c2b = *reinterpret_cast<const float4*>(row + 256 + u0 * 5 + 4);
            const float4 c2c = *reinterpret_cast<const float4*>(row + 256 + u0 * 5 + 8);
            const float4 c2d = *reinterpret_cast<const float4*>(row + 256 + u0 * 5 + 12);
            const float4 c2e = *reinterpret_cast<const float4*>(row + 256 + u0 * 5 + 16);
            o9[0] += c0.x * w0[0] + c0.y * w0[1] + c0.z * w0[2] + c0.w * w0[3];
            o9[1] += c1a.x * w1[0] + c1a.w * w1[1] + c1b.z * w1[2] + c1c.y * w1[3];
            o9[2] += c1a.y * w1[0] + c1b.x * w1[1] + c1b.w * w1[2] + c1c.z * w1[3];
            o9[3] += c1a.z * w1[0] + c1b.y * w1[1] + c1c.x * w1[2] + c1c.w * w1[3];
            o9[4] += c2a.x * w2[0] + c2b.y * w2[1] + c2c.z * w2[2] + c2d.w * w2[3];
            o9[5] += c2a.y * w2[0] + c2b.z * w2[1] + c2c.w * w2[2] + c2e.x * w2[3];
            o9[6] += c2a.z * w2[0] + c2b.w * w2[1] + c2d.x * w2[2] + c2e.y * w2[3];
            o9[7] += c2a.w * w2[0] + c2c.x * w2[1] + c2d.y * w2[2] + c2e.z * w2[3];
            o9[8] += c2b.x * w2[0] + c2c.y * w2[1] + c2d.z * w2[2] + c2e.w * w2[3];
        }
    }
    #pragma unroll
    for (int rr = 0; rr < 4; ++rr) {
        float* op = out + ((size_t)blockIdx.x * 16 + r0 + rr) * MSG_DIM + lane * 9;
        #pragma unroll
        for (int m = 0; m < 9; ++m) op[m] = o[rr][m] * scale;
    }
}

// ---------------------------------------------------------------------------
extern "C" void kernel_launch(void* const* d_in, const int* in_sizes, int n_in,
                              void* d_out, int out_size, void* d_ws, size_t ws_size,
                              hipStream_t stream) {
    const float* node_attrs = (const float*)d_in[0];
    const float* node_feats = (const float*)d_in[1];
    const float* edge_attrs = (const float*)d_in[2];
    const float* edge_feats = (const float*)d_in[3];
    const int*   edge_index = (const int*)d_in[4];
    const float* W_lin1 = (const float*)d_in[5];
    const float* W_r0 = (const float*)d_in[6];
    const float* W_r1 = (const float*)d_in[7];
    const float* W_r2 = (const float*)d_in[8];
    const float* W_r3 = (const float*)d_in[9];
    const float* W_msg = (const float*)d_in[10];
    const float* W_skip = (const float*)d_in[11];

    float* out = (float*)d_out;                       // N x 576 (msg -> transformed in place)
    float* sc  = out + (size_t)N_NODES * MSG_DIM;     // N x 64

    float* wsf = (float*)d_ws;
    float* Wc = wsf;                          // 2048 floats
    float* h  = wsf + 2048;                   // N*64
    int* wsi   = (int*)(wsf + 2048 + (size_t)N_NODES * 64);
    int* counts = wsi;                        // N
    int* start  = wsi + N_NODES;              // N
    int* cursor = wsi + 2 * N_NODES;          // N
    float* rec  = (float*)(wsi + 3 * N_NODES);        // (E+16) * REC floats

    hipMemsetAsync(counts, 0, N_NODES * sizeof(int), stream);
    node_linear_hist_skip<<<1250, 256, 0, stream>>>(node_feats, W_lin1, h,
                                                    edge_index, counts,
                                                    node_attrs, W_skip, sc);
    scan_radial_kernel<<<1, 1024, 0, stream>>>(counts, start, cursor,
                                               W_r0, W_r1, W_r2, W_r3, Wc, rec);
    scatter_build<<<1250, 256, 0, stream>>>(
        edge_index, edge_feats, edge_attrs, cursor, rec);
    gather_sorted<<<N_NODES / 2, 256, 0, stream>>>(
        rec, h, Wc, start, counts, out);
    out_transform<<<1250, 256, 0, stream>>>(W_msg, out);
}